// Round 6
// baseline (249.244 us; speedup 1.0000x reference)
//
#include <hip/hip_runtime.h>
#include <hip/hip_fp16.h>
#include <math.h>

#define N_NODES 10000
#define E_EDGES 160000
#define DMODEL 64
#define H 4
#define NBOUND 31
// qall record per node (fp16, 1024 halves):
//  [0:512)   P: for (h,c): 8 halves = [hvals(4) | q1vals(4)]  at (h*16+c)*8
//  [512:768) q2: h*64 + d
//  [768:1024) q3: h*64 + d
#define QREC 1024

typedef _Float16 half8 __attribute__((ext_vector_type(8)));
typedef float floatx4 __attribute__((ext_vector_type(4)));

// ---------------------------------------------------------------------------
// P1: B[kh] = fck (128x64) @ F (64x64) -> Bws.  12 blocks.
// ---------------------------------------------------------------------------
__global__ __launch_bounds__(256) void pre1_kernel(
    const float* __restrict__ fc1, const float* __restrict__ fc2,
    const float* __restrict__ fc3, const float* __restrict__ fcc,
    float* __restrict__ Bws) {
  __shared__ __align__(16) float S[12288];  // [0:8192) fck, [8192:12288) F
  int kh = blockIdx.x;
  int k = kh >> 2, h = kh & 3;
  const float* fck = (k == 0) ? fc1 : (k == 1) ? fc2 : fc3;
  fck += h * 128 * 64;
  const float* F = fcc + h * 192 * 64 + k * 64 * 64;
  int tid = threadIdx.x;
  #pragma unroll
  for (int u = 0; u < 8; ++u)
    ((float4*)S)[u * 256 + tid] = ((const float4*)fck)[u * 256 + tid];
  #pragma unroll
  for (int u = 0; u < 4; ++u)
    ((float4*)(S + 8192))[u * 256 + tid] = ((const float4*)F)[u * 256 + tid];
  __syncthreads();
  int j = tid & 63, ig = tid >> 6;
  #pragma unroll
  for (int rg = 0; rg < 8; ++rg) {
    int i0 = ig * 32 + rg * 4;
    float a0 = 0.f, a1 = 0.f, a2 = 0.f, a3 = 0.f;
    #pragma unroll
    for (int t4 = 0; t4 < 16; ++t4) {
      float4 f0 = *(const float4*)&S[(i0 + 0) * 64 + t4 * 4];
      float4 f1 = *(const float4*)&S[(i0 + 1) * 64 + t4 * 4];
      float4 f2 = *(const float4*)&S[(i0 + 2) * 64 + t4 * 4];
      float4 f3 = *(const float4*)&S[(i0 + 3) * 64 + t4 * 4];
      float b0 = S[8192 + (t4 * 4 + 0) * 64 + j];
      float b1 = S[8192 + (t4 * 4 + 1) * 64 + j];
      float b2 = S[8192 + (t4 * 4 + 2) * 64 + j];
      float b3 = S[8192 + (t4 * 4 + 3) * 64 + j];
      a0 += f0.x * b0 + f0.y * b1 + f0.z * b2 + f0.w * b3;
      a1 += f1.x * b0 + f1.y * b1 + f1.z * b2 + f1.w * b3;
      a2 += f2.x * b0 + f2.y * b1 + f2.z * b2 + f2.w * b3;
      a3 += f3.x * b0 + f3.y * b1 + f3.z * b2 + f3.w * b3;
    }
    Bws[kh * 8192 + (i0 + 0) * 64 + j] = a0;
    Bws[kh * 8192 + (i0 + 1) * 64 + j] = a1;
    Bws[kh * 8192 + (i0 + 2) * 64 + j] = a2;
    Bws[kh * 8192 + (i0 + 3) * 64 + j] = a3;
  }
}

// ---------------------------------------------------------------------------
// P2: 60 blocks = 12 kh x 5 roles.
//  role 0-3: WC rows r0=role*32..+31: Wfc_h @ B1 -> bigWT (fp16, [n][k])
//            (k==0 also copies Wfc slice into bigWT block 0)
//  role 4  : GB = G_h @ B2; U = emb @ GB -> U16 (fp16)
// ---------------------------------------------------------------------------
__global__ __launch_bounds__(256) void pre2_kernel(
    const float* __restrict__ Wfc, const float* __restrict__ G,
    const float* __restrict__ emb, const float* __restrict__ Bws,
    __half* __restrict__ bigWT, __half* __restrict__ U16) {
  __shared__ __align__(16) float S[9216];
  int bi = blockIdx.x;
  int kh = bi / 5, role = bi % 5;
  int k = kh >> 2, h = kh & 3;
  int tid = threadIdx.x;
  int j = tid & 63;
  if (role < 4) {
    int r0 = role * 32;
    #pragma unroll
    for (int u = 0; u < 4; ++u)
      ((float4*)S)[u * 256 + tid] = ((const float4*)(Bws + kh * 8192))[u * 256 + tid];
    #pragma unroll
    for (int u = 0; u < 2; ++u) {
      int fi = u * 256 + tid;
      int i = fi >> 4, c4 = fi & 15;
      ((float4*)(S + 4096))[fi] =
          ((const float4*)(Wfc + (r0 + i) * 256 + h * 64))[c4];
    }
    __syncthreads();
    int ig = tid >> 6;
    int i0 = ig * 8;
    #pragma unroll
    for (int g4 = 0; g4 < 2; ++g4) {
      int ib = i0 + g4 * 4;
      float a0 = 0.f, a1 = 0.f, a2 = 0.f, a3 = 0.f;
      #pragma unroll
      for (int t4 = 0; t4 < 16; ++t4) {
        float4 f0 = *(const float4*)&S[4096 + (ib + 0) * 64 + t4 * 4];
        float4 f1 = *(const float4*)&S[4096 + (ib + 1) * 64 + t4 * 4];
        float4 f2 = *(const float4*)&S[4096 + (ib + 2) * 64 + t4 * 4];
        float4 f3 = *(const float4*)&S[4096 + (ib + 3) * 64 + t4 * 4];
        float b0 = S[(t4 * 4 + 0) * 64 + j];
        float b1 = S[(t4 * 4 + 1) * 64 + j];
        float b2 = S[(t4 * 4 + 2) * 64 + j];
        float b3 = S[(t4 * 4 + 3) * 64 + j];
        a0 += f0.x * b0 + f0.y * b1 + f0.z * b2 + f0.w * b3;
        a1 += f1.x * b0 + f1.y * b1 + f1.z * b2 + f1.w * b3;
        a2 += f2.x * b0 + f2.y * b1 + f2.z * b2 + f2.w * b3;
        a3 += f3.x * b0 + f3.y * b1 + f3.z * b2 + f3.w * b3;
      }
      __half hv[4] = {__float2half(a0), __float2half(a1), __float2half(a2),
                      __float2half(a3)};
      *(uint2*)&bigWT[((k + 1) * 256 + h * 64 + j) * 128 + r0 + ib] =
          *(uint2*)hv;
    }
    if (k == 0) {
      #pragma unroll
      for (int u = 0; u < 8; ++u) {
        int idx = u * 256 + tid;
        int i = idx >> 6, jj = idx & 63;
        bigWT[(h * 64 + jj) * 128 + r0 + i] = __float2half(S[4096 + idx]);
      }
    }
  } else {
    // [0:4096) B2, [4096:6144) G, [6144:7168) emb, [7168:9216) GB
    #pragma unroll
    for (int u = 0; u < 4; ++u)
      ((float4*)S)[u * 256 + tid] =
          ((const float4*)(Bws + kh * 8192 + 4096))[u * 256 + tid];
    #pragma unroll
    for (int u = 0; u < 2; ++u)
      ((float4*)(S + 4096))[u * 256 + tid] =
          ((const float4*)(G + h * 2048))[u * 256 + tid];
    ((float4*)(S + 6144))[tid] = ((const float4*)emb)[tid];
    __syncthreads();
    int wv = tid >> 6;
    #pragma unroll
    for (int rg = 0; rg < 2; ++rg) {
      int g0 = wv * 8 + rg * 4;
      float a0 = 0.f, a1 = 0.f, a2 = 0.f, a3 = 0.f;
      #pragma unroll
      for (int t4 = 0; t4 < 16; ++t4) {
        float4 f0 = *(const float4*)&S[4096 + (g0 + 0) * 64 + t4 * 4];
        float4 f1 = *(const float4*)&S[4096 + (g0 + 1) * 64 + t4 * 4];
        float4 f2 = *(const float4*)&S[4096 + (g0 + 2) * 64 + t4 * 4];
        float4 f3 = *(const float4*)&S[4096 + (g0 + 3) * 64 + t4 * 4];
        float b0 = S[(t4 * 4 + 0) * 64 + j];
        float b1 = S[(t4 * 4 + 1) * 64 + j];
        float b2 = S[(t4 * 4 + 2) * 64 + j];
        float b3 = S[(t4 * 4 + 3) * 64 + j];
        a0 += f0.x * b0 + f0.y * b1 + f0.z * b2 + f0.w * b3;
        a1 += f1.x * b0 + f1.y * b1 + f1.z * b2 + f1.w * b3;
        a2 += f2.x * b0 + f2.y * b1 + f2.z * b2 + f2.w * b3;
        a3 += f3.x * b0 + f3.y * b1 + f3.z * b2 + f3.w * b3;
      }
      S[7168 + (g0 + 0) * 64 + j] = a0;
      S[7168 + (g0 + 1) * 64 + j] = a1;
      S[7168 + (g0 + 2) * 64 + j] = a2;
      S[7168 + (g0 + 3) * 64 + j] = a3;
    }
    __syncthreads();
    #pragma unroll
    for (int rg = 0; rg < 2; ++rg) {
      int e0 = wv * 8 + rg * 4;
      float a0 = 0.f, a1 = 0.f, a2 = 0.f, a3 = 0.f;
      #pragma unroll
      for (int t4 = 0; t4 < 8; ++t4) {
        float4 f0 = *(const float4*)&S[6144 + (e0 + 0) * 32 + t4 * 4];
        float4 f1 = *(const float4*)&S[6144 + (e0 + 1) * 32 + t4 * 4];
        float4 f2 = *(const float4*)&S[6144 + (e0 + 2) * 32 + t4 * 4];
        float4 f3 = *(const float4*)&S[6144 + (e0 + 3) * 32 + t4 * 4];
        float b0 = S[7168 + (t4 * 4 + 0) * 64 + j];
        float b1 = S[7168 + (t4 * 4 + 1) * 64 + j];
        float b2 = S[7168 + (t4 * 4 + 2) * 64 + j];
        float b3 = S[7168 + (t4 * 4 + 3) * 64 + j];
        a0 += f0.x * b0 + f0.y * b1 + f0.z * b2 + f0.w * b3;
        a1 += f1.x * b0 + f1.y * b1 + f1.z * b2 + f1.w * b3;
        a2 += f2.x * b0 + f2.y * b1 + f2.z * b2 + f2.w * b3;
        a3 += f3.x * b0 + f3.y * b1 + f3.z * b2 + f3.w * b3;
      }
      int base = k * 8192 + h * 2048;
      U16[base + (e0 + 0) * 64 + j] = __float2half(a0);
      U16[base + (e0 + 1) * 64 + j] = __float2half(a1);
      U16[base + (e0 + 2) * 64 + j] = __float2half(a2);
      U16[base + (e0 + 3) * 64 + j] = __float2half(a3);
    }
  }
}

// ---------------------------------------------------------------------------
// prep: zero counts + pack pos into float4 (one 16B gather later instead of
// 3 scalar loads). Replaces the memset dispatch.
// ---------------------------------------------------------------------------
__global__ __launch_bounds__(256) void prep_kernel(const float* __restrict__ pos,
                                                   float4* __restrict__ pos4,
                                                   int* __restrict__ counts) {
  int n = blockIdx.x * 256 + threadIdx.x;
  if (n < N_NODES) {
    counts[n] = 0;
    pos4[n] = make_float4(pos[n * 3], pos[n * 3 + 1], pos[n * 3 + 2], 0.f);
  }
}

// ---------------------------------------------------------------------------
// K1: qall(fp16, permuted layout) = feat(fp32) @ bigWT^T via MFMA 16x16x32.
// Region (h/q1/q2/q3) and head are block-uniform (n-tile = 64 within a 256
// region). h+q1 interleaved into P region for single-load gathers.
// ---------------------------------------------------------------------------
__global__ __launch_bounds__(256) void gemm_kernel(
    const float* __restrict__ feat, const __half* __restrict__ bigWT,
    __half* __restrict__ qall) {
  int tid = threadIdx.x;
  int wv = tid >> 6, l = tid & 63;
  int m0 = blockIdx.x * 64 + wv * 16;
  int n0 = blockIdx.y * 64;
  int lm = l & 15, lk = (l >> 4) * 8;
  int arow = m0 + lm;
  if (arow >= N_NODES) arow = N_NODES - 1;
  const float* fp = feat + arow * 128 + lk;
  const _Float16* bp = (const _Float16*)bigWT + lk;
  floatx4 acc[4];
  #pragma unroll
  for (int nt = 0; nt < 4; ++nt) acc[nt] = (floatx4){0.f, 0.f, 0.f, 0.f};
  #pragma unroll
  for (int kt = 0; kt < 4; ++kt) {
    float4 f0 = *(const float4*)(fp + kt * 32);
    float4 f1 = *(const float4*)(fp + kt * 32 + 4);
    half8 a;
    a[0] = (_Float16)f0.x; a[1] = (_Float16)f0.y;
    a[2] = (_Float16)f0.z; a[3] = (_Float16)f0.w;
    a[4] = (_Float16)f1.x; a[5] = (_Float16)f1.y;
    a[6] = (_Float16)f1.z; a[7] = (_Float16)f1.w;
    #pragma unroll
    for (int nt = 0; nt < 4; ++nt) {
      half8 b = *(const half8*)(bp + (n0 + nt * 16 + lm) * 128 + kt * 32);
      acc[nt] = __builtin_amdgcn_mfma_f32_16x16x32_f16(a, b, acc[nt], 0, 0, 0);
    }
  }
  int reg = n0 >> 8;             // 0=h,1=q1,2=q2,3=q3 (block-uniform)
  int hh = (n0 & 255) >> 6;      // head (block-uniform)
  int mrow = m0 + (l >> 4) * 4;
  #pragma unroll
  for (int nt = 0; nt < 4; ++nt) {
    #pragma unroll
    for (int r4 = 0; r4 < 4; ++r4) {
      int m = mrow + r4;
      if (m < N_NODES) {
        int dd = nt * 16 + lm;
        int off;
        if (reg == 0)      off = (hh * 16 + (dd >> 2)) * 8 + (dd & 3);
        else if (reg == 1) off = (hh * 16 + (dd >> 2)) * 8 + 4 + (dd & 3);
        else if (reg == 2) off = 512 + hh * 64 + dd;
        else               off = 768 + hh * 64 + dd;
        qall[m * QREC + off] = __float2half(acc[nt][r4]);
      }
    }
  }
}

// ---------------------------------------------------------------------------
// CSR build
// ---------------------------------------------------------------------------
__global__ __launch_bounds__(256) void count_kernel(const int* __restrict__ dst,
                                                    int* __restrict__ counts) {
  int e = blockIdx.x * 256 + threadIdx.x;
  if (e < E_EDGES) atomicAdd(&counts[dst[e]], 1);
}

__global__ __launch_bounds__(1024) void scan_kernel(const int* __restrict__ counts,
                                                    int* __restrict__ starts,
                                                    int* __restrict__ cursor) {
  __shared__ int lds[1024];
  int tid = threadIdx.x;
  int base = tid * 10;
  int loc[10];
  int s = 0;
  #pragma unroll
  for (int u = 0; u < 10; ++u) {
    int i = base + u;
    int v = (i < N_NODES) ? counts[i] : 0;
    loc[u] = s;
    s += v;
  }
  lds[tid] = s;
  __syncthreads();
  int inc = s;
  for (int off = 1; off < 1024; off <<= 1) {
    int y = (tid >= off) ? lds[tid - off] : 0;
    __syncthreads();
    inc += y;
    lds[tid] = inc;
    __syncthreads();
  }
  int excl = inc - s;
  #pragma unroll
  for (int u = 0; u < 10; ++u) {
    int i = base + u;
    if (i < N_NODES) {
      int v = excl + loc[u];
      starts[i] = v;
      cursor[i] = v;
    }
  }
  if (tid == 1023) starts[N_NODES] = inc;
}

__global__ __launch_bounds__(256) void fill_kernel(const int* __restrict__ dst,
                                                   int* __restrict__ cursor,
                                                   int* __restrict__ elist) {
  int e = blockIdx.x * 256 + threadIdx.x;
  if (e < E_EDGES) {
    int p = atomicAdd(&cursor[dst[e]], 1);
    elist[p] = e;
  }
}

// ---------------------------------------------------------------------------
// K3: FUSED score + softmax + aggregate (max-free; |score| <= ~15).
// Block = dst node; 4 waves stride edges; lane: h=lane>>4, c=lane&15.
// Gathers per edge-head: P(16B: h|q1), q2(8B), U1/U2/U3(8B fp16), pos4 x2.
// ---------------------------------------------------------------------------
__device__ __forceinline__ int didx(const float* __restrict__ bnd2, float d) {
  int g = (int)(d * 10.0f);
  g = (g < 0) ? 0 : ((g > 31) ? 31 : g);
  g += (bnd2[g + 1] < d) ? 1 : 0;
  g -= (bnd2[g] >= d) ? 1 : 0;
  return g;
}

__device__ __forceinline__ float fast_tanh(float z) {
  float a = fabsf(z);
  float p = __expf(2.0f * a);
  float r = 1.0f - 2.0f / (p + 1.0f);
  return copysignf(r, z);
}

__device__ __forceinline__ float dpp_row_sum16(float v) {
  int x;
  x = __builtin_amdgcn_update_dpp(0, __float_as_int(v), 0x128, 0xf, 0xf, true);
  v += __int_as_float(x);
  x = __builtin_amdgcn_update_dpp(0, __float_as_int(v), 0x124, 0xf, 0xf, true);
  v += __int_as_float(x);
  x = __builtin_amdgcn_update_dpp(0, __float_as_int(v), 0x122, 0xf, 0xf, true);
  v += __int_as_float(x);
  x = __builtin_amdgcn_update_dpp(0, __float_as_int(v), 0x121, 0xf, 0xf, true);
  v += __int_as_float(x);
  return v;
}

__device__ __forceinline__ float4 h4_to_f4(uint2 u) {
  union { uint2 ui; __half2 h[2]; } cc;
  cc.ui = u;
  float2 a = __half22float2(cc.h[0]);
  float2 b = __half22float2(cc.h[1]);
  return make_float4(a.x, a.y, b.x, b.y);
}

__device__ __forceinline__ void fma4(float4& a, float s, const float4& b) {
  a.x += s * b.x; a.y += s * b.y; a.z += s * b.z; a.w += s * b.w;
}

__global__ __launch_bounds__(256) void fused_kernel(
    const int* __restrict__ starts, const int* __restrict__ elist,
    const int* __restrict__ src, const int* __restrict__ inter,
    const float4* __restrict__ pos4, const float* __restrict__ boundaries,
    const __half* __restrict__ qall, const __half* __restrict__ U16,
    const float* __restrict__ aout, float* __restrict__ out) {
  __shared__ float bnd2[33];
  __shared__ float4 sm_num[4][64];
  __shared__ float sm_den[4][4];
  __shared__ float sm_red[4][64];
  int tid = threadIdx.x;
  if (tid < NBOUND) bnd2[tid + 1] = boundaries[tid];
  if (tid == NBOUND) { bnd2[0] = -INFINITY; bnd2[32] = INFINITY; }
  __syncthreads();
  int w = tid >> 6;
  int lane = tid & 63;
  int h = lane >> 4;
  int c = lane & 15;
  int n = blockIdx.x;
  int b = starts[n], e_end = starts[n + 1];
  float4 tp = pos4[n];
  const float4 q3f = h4_to_f4(*(const uint2*)(qall + n * QREC + 768 + h * 64 + c * 4));
  const float4 a4 = *((const float4*)(aout + h * 64) + c);
  float4 acc = make_float4(0.f, 0.f, 0.f, 0.f);
  float den = 0.f;
  int i = b + w;
  float4 ps = tp, pi = tp;
  uint4 rP = {0, 0, 0, 0};
  uint2 rQ2 = {0, 0};
  if (i < e_end) {
    int e = elist[i];
    int s = src[e];
    int it = inter[e * H + h];
    ps = pos4[s];
    pi = pos4[it];
    rP = *(const uint4*)(qall + s * QREC + (h * 16 + c) * 8);
    rQ2 = *(const uint2*)(qall + it * QREC + 512 + h * 64 + c * 4);
  }
  while (i < e_end) {
    int inext = i + 4;
    float4 psn = tp, pin = tp;
    uint4 rPn = {0, 0, 0, 0};
    uint2 rQ2n = {0, 0};
    if (inext < e_end) {
      int en = elist[inext];
      int sn = src[en];
      int itn = inter[en * H + h];
      psn = pos4[sn];
      pin = pos4[itn];
      rPn = *(const uint4*)(qall + sn * QREC + (h * 16 + c) * 8);
      rQ2n = *(const uint2*)(qall + itn * QREC + 512 + h * 64 + c * 4);
    }
    float dx = tp.x - ps.x, dy = tp.y - ps.y, dz = tp.z - ps.z;
    float dist1 = sqrtf(dx * dx + dy * dy + dz * dz);
    float ax = tp.x - pi.x, ay = tp.y - pi.y, az = tp.z - pi.z;
    float dist2 = sqrtf(ax * ax + ay * ay + az * az);
    float bx = ps.x - pi.x, by = ps.y - pi.y, bz = ps.z - pi.z;
    float dist_ = sqrtf(bx * bx + by * by + bz * bz);
    int idx1 = didx(bnd2, dist1);
    int idx2 = didx(bnd2, dist2);
    int idx_ = didx(bnd2, dist_);
    const float4 X = h4_to_f4(*(const uint2*)(U16 + (h * 32 + idx1) * 64 + c * 4));
    const float4 Y = h4_to_f4(*(const uint2*)(U16 + 8192 + (h * 32 + idx2) * 64 + c * 4));
    const float4 Z = h4_to_f4(*(const uint2*)(U16 + 16384 + (h * 32 + idx_) * 64 + c * 4));
    const float4 hb = h4_to_f4(make_uint2(rP.x, rP.y));
    const float4 A = h4_to_f4(make_uint2(rP.z, rP.w));
    const float4 B = h4_to_f4(rQ2);
    float t0 = fast_tanh(A.x + B.x + q3f.x + X.x + Y.x + Z.x);
    float t1 = fast_tanh(A.y + B.y + q3f.y + X.y + Y.y + Z.y);
    float t2 = fast_tanh(A.z + B.z + q3f.z + X.z + Y.z + Z.z);
    float t3 = fast_tanh(A.w + B.w + q3f.w + X.w + Y.w + Z.w);
    float v = t0 * a4.x + t1 * a4.y + t2 * a4.z + t3 * a4.w;
    v = dpp_row_sum16(v);
    float ex = __expf(v);
    den += ex;
    fma4(acc, ex, hb);
    i = inext;
    ps = psn; pi = pin; rP = rPn; rQ2 = rQ2n;
  }
  sm_num[w][lane] = acc;
  if (c == 0) sm_den[w][h] = den;
  __syncthreads();
  int hh = tid >> 6, d = tid & 63;
  float dsum = sm_den[0][hh] + sm_den[1][hh] + sm_den[2][hh] + sm_den[3][hh];
  float v = 0.f;
  #pragma unroll
  for (int wv = 0; wv < 4; ++wv)
    v += ((const float*)&sm_num[wv][hh * 16 + (d >> 2)])[d & 3];
  sm_red[hh][d] = (e_end > b) ? (v / dsum) : 0.f;
  __syncthreads();
  if (tid < 64) {
    out[n * 64 + tid] = 0.25f * (sm_red[0][tid] + sm_red[1][tid] +
                                 sm_red[2][tid] + sm_red[3][tid]);
  }
}

// ---------------------------------------------------------------------------
extern "C" void kernel_launch(void* const* d_in, const int* in_sizes, int n_in,
                              void* d_out, int out_size, void* d_ws,
                              size_t ws_size, hipStream_t stream) {
  const float* feat = (const float*)d_in[0];
  const float* loc = (const float*)d_in[1];
  const int* src = (const int*)d_in[2];
  const int* dst = (const int*)d_in[3];
  const int* inter = (const int*)d_in[4];
  const float* Wfc = (const float*)d_in[5];
  const float* emb = (const float*)d_in[6];
  const float* G = (const float*)d_in[7];
  const float* fc1 = (const float*)d_in[8];
  const float* fc2 = (const float*)d_in[9];
  const float* fc3 = (const float*)d_in[10];
  const float* fcc = (const float*)d_in[11];
  const float* aout = (const float*)d_in[12];
  const float* bnd = (const float*)d_in[13];
  float* out = (float*)d_out;

  __half* qall = (__half*)d_ws;                    // N*1024 halfs (20.48 MB)
  __half* bigWT = qall + N_NODES * QREC;           // 1024*128 halfs
  __half* U16 = bigWT + 1024 * 128;                // 3*4*2048 halfs
  float* Bws = (float*)(U16 + 3 * H * 2048);       // 12*8192 f32
  float4* pos4 = (float4*)(Bws + 12 * 8192);       // N float4
  int* counts = (int*)(pos4 + N_NODES);            // N
  int* starts = counts + N_NODES;                  // N+1
  int* cursor = starts + N_NODES + 1;              // N
  int* elist = cursor + N_NODES;                   // E

  prep_kernel<<<(N_NODES + 255) / 256, 256, 0, stream>>>(loc, pos4, counts);
  count_kernel<<<(E_EDGES + 255) / 256, 256, 0, stream>>>(dst, counts);
  pre1_kernel<<<12, 256, 0, stream>>>(fc1, fc2, fc3, fcc, Bws);
  pre2_kernel<<<60, 256, 0, stream>>>(Wfc, G, emb, Bws, bigWT, U16);
  scan_kernel<<<1, 1024, 0, stream>>>(counts, starts, cursor);
  fill_kernel<<<(E_EDGES + 255) / 256, 256, 0, stream>>>(dst, cursor, elist);
  dim3 ggrid((N_NODES + 63) / 64, 16);
  gemm_kernel<<<ggrid, 256, 0, stream>>>(feat, bigWT, qall);
  fused_kernel<<<N_NODES, 256, 0, stream>>>(starts, elist, src, inter, pos4,
                                            bnd, qall, U16, aout, out);
}